// Round 16
// baseline (2037.658 us; speedup 1.0000x reference)
//
#include <hip/hip_runtime.h>

// ---- problem constants ----
constexpr int   NN  = 50000;            // nodes
constexpr int   NE  = 600000;           // edges
constexpr int   EA  = NE + NN;          // augmented edges (self loops appended)
constexpr int   ND  = 128;              // node dim
constexpr int   ED  = 64;               // edge dim
constexpr int   HD  = 128;              // hidden dim

// =====================================================================
// CSR build: histogram -> prefix scan -> scatter (+ sorted src/dst)
// =====================================================================
__global__ void k_hist(const int* __restrict__ src, const int* __restrict__ dst,
                       int* __restrict__ cntS, int* __restrict__ cntD)
{
    int e = blockIdx.x * 256 + threadIdx.x;
    if (e >= NE) return;
    atomicAdd(&cntS[src[e]], 1);
    atomicAdd(&cntD[dst[e]], 1);
}

__global__ __launch_bounds__(1024) void k_scan(
    const int* __restrict__ cntS, const int* __restrict__ cntD,
    int* __restrict__ rpS, int* __restrict__ rpD,
    int* __restrict__ curS, int* __restrict__ curD)
{
    __shared__ int part[1024];
    const int tid = threadIdx.x;
    constexpr int CH = (NN + 1023) / 1024;
    for (int pass = 0; pass < 2; ++pass) {
        const int* cnt = pass ? cntD : cntS;
        int* rp  = pass ? rpD  : rpS;
        int* cur = pass ? curD : curS;
        int i0 = tid * CH, i1 = (i0 + CH < NN) ? i0 + CH : NN;
        int ls = 0;
        for (int i = i0; i < i1; ++i) ls += cnt[i];
        part[tid] = ls;
        __syncthreads();
        for (int off = 1; off < 1024; off <<= 1) {
            int v = (tid >= off) ? part[tid - off] : 0;
            __syncthreads();
            part[tid] += v;
            __syncthreads();
        }
        int run = tid ? part[tid - 1] : 0;
        for (int i = i0; i < i1; ++i) { rp[i] = run; cur[i] = run; run += cnt[i]; }
        if (tid == 1023) rp[NN] = run;
        __syncthreads();
    }
}

__global__ void k_scatter(const int* __restrict__ src, const int* __restrict__ dst,
                          int* __restrict__ curS, int* __restrict__ curD,
                          int* __restrict__ eidS, int* __restrict__ eidD,
                          int* __restrict__ srcS, int* __restrict__ dstS)
{
    int e = blockIdx.x * 256 + threadIdx.x;
    if (e >= NE) return;
    int s = src[e], d = dst[e];
    eidS[atomicAdd(&curS[s], 1)] = e;
    int pd = atomicAdd(&curD[d], 1);
    eidD[pd] = e;
    srcS[pd] = s;
    dstS[pd] = d;
}

// =====================================================================
// K1a/K1b: node-centric edge-projection means, split into src and dst
//   passes (edge_attr fits L3: pass 2 re-reads mostly from L3 instead of
//   HBM -- r15 FETCH was 2x154MB). One wave per node. Lane owns ADJACENT
//   cols (2*lane, 2*lane+1): per-k weight reload is one dwordx2.
// =====================================================================
__global__ __launch_bounds__(64) void k_node_src(
    const float* __restrict__ eattr,
    const int* __restrict__ rpS, const int* __restrict__ eidS,
    const float* __restrict__ ep_w, const float* __restrict__ ep_b,
    float* __restrict__ x_input)
{
    const int lane = threadIdx.x;
    const int n = blockIdx.x;
    const int c = lane * 2;

    const float2 bb = *(const float2*)&ep_b[c];

    float a0 = 0.f, a1 = 0.f;
    const int s0 = rpS[n], s1 = rpS[n + 1];
    for (int i = s0; i < s1; ++i) {
        const int e = __builtin_amdgcn_readfirstlane(eidS[i]);
        const float* ea = eattr + (long)e * ED;
        float d0 = bb.x, d1 = bb.y;
        #pragma unroll
        for (int k = 0; k < 64; ++k) {
            const float a = ea[k];                           // uniform -> s_load
            const float2 w = *(const float2*)&ep_w[k * ND + c];  // one dwordx2
            d0 = fmaf(a, w.x, d0);
            d1 = fmaf(a, w.y, d1);
        }
        a0 += fmaxf(d0, 0.f);
        a1 += fmaxf(d1, 0.f);
    }
    const float inv = 1.f / (float)((s1 - s0) > 1 ? (s1 - s0) : 1);
    *(float2*)&x_input[(long)n * 256 + c] = make_float2(a0 * inv, a1 * inv);
}

__global__ __launch_bounds__(64) void k_node_dst(
    const float* __restrict__ eattr,
    const int* __restrict__ rpD, const int* __restrict__ eidD,
    const float* __restrict__ ep_w, const float* __restrict__ ep_b,
    float* __restrict__ x_input, float* __restrict__ loopa)
{
    const int lane = threadIdx.x;
    const int n = blockIdx.x;
    const int c = lane * 2;

    const float2 bb = *(const float2*)&ep_b[c];

    float a0 = 0.f, a1 = 0.f, la = 0.f;
    const int d0i = rpD[n], d1i = rpD[n + 1];
    for (int i = d0i; i < d1i; ++i) {
        const int e = __builtin_amdgcn_readfirstlane(eidD[i]);
        const float* ea = eattr + (long)e * ED;
        la += ea[lane];
        float d0 = bb.x, d1 = bb.y;
        #pragma unroll
        for (int k = 0; k < 64; ++k) {
            const float a = ea[k];
            const float2 w = *(const float2*)&ep_w[k * ND + c];
            d0 = fmaf(a, w.x, d0);
            d1 = fmaf(a, w.y, d1);
        }
        a0 += fmaxf(d0, 0.f);
        a1 += fmaxf(d1, 0.f);
    }
    const float inv = 1.f / (float)((d1i - d0i) > 1 ? (d1i - d0i) : 1);
    *(float2*)&x_input[(long)n * 256 + 128 + c] = make_float2(a0 * inv, a1 * inv);
    loopa[(long)n * ED + lane] = la * inv;
}

// =====================================================================
// K3: dual-output dense GEMM -- C1 = A@W1, C2 = A@W2 (shared A staging).
// =====================================================================
template<int KD, int NC>
__global__ __launch_bounds__(512) void k_gemm2(const float* __restrict__ A,
                                               const float* __restrict__ W1,
                                               const float* __restrict__ W2,
                                               float* __restrict__ C1,
                                               float* __restrict__ C2, int M)
{
    constexpr int CPW = NC / 8;                    // 32 (NC=256) / 16 (NC=128)
    __shared__ float a_lds[64][65];
    const int lane = threadIdx.x & 63;
    const int wid  = __builtin_amdgcn_readfirstlane(threadIdx.x >> 6);   // 0..7
    const int r0   = blockIdx.x * 64;
    const int row  = r0 + lane;

    float acc1[CPW], acc2[CPW];
    #pragma unroll
    for (int j = 0; j < CPW; ++j) { acc1[j] = 0.f; acc2[j] = 0.f; }

    for (int k0 = 0; k0 < KD; k0 += 64) {
        __syncthreads();
        for (int r = wid; r < 64; r += 8) {
            int rr = r0 + r;
            a_lds[r][lane] = (rr < M) ? A[(long)rr * KD + k0 + lane] : 0.f;
        }
        __syncthreads();
        for (int k = 0; k < 64; ++k) {
            float a = a_lds[lane][k];
            const float* w1row = W1 + (long)(k0 + k) * NC + wid * CPW;
            const float* w2row = W2 + (long)(k0 + k) * NC + wid * CPW;
            #pragma unroll
            for (int j = 0; j < CPW; ++j) {
                acc1[j] = fmaf(a, w1row[j], acc1[j]);
                acc2[j] = fmaf(a, w2row[j], acc2[j]);
            }
        }
    }
    if (row < M) {
        float* c1row = C1 + (long)row * NC + wid * CPW;
        float* c2row = C2 + (long)row * NC + wid * CPW;
        #pragma unroll
        for (int j = 0; j < CPW; ++j) { c1row[j] = acc1[j]; c2row[j] = acc2[j]; }
    }
}

// =====================================================================
// K4: edge-parallel logits, 2 positions per lane (register blocking).
// =====================================================================
template<int HEADS>
__global__ __launch_bounds__(256) void k_gat_logits(
    const float* __restrict__ eattr,
    const int* __restrict__ eidD, const int* __restrict__ srcS, const int* __restrict__ dstS,
    const float* __restrict__ loopa,
    const float* __restrict__ xl, const float* __restrict__ xr,
    const float* __restrict__ we, const float* __restrict__ att,
    float* __restrict__ logits)
{
    constexpr int OC    = HEADS * 128;
    constexpr int CPW   = OC / 4;                  // 64 (H=2) / 32 (H=1)
    constexpr int NPASS = CPW / 32;                // 2 / 1
    __shared__ float ea_lds[128][65];
    __shared__ float p_lds[4][128];
    const int lane = threadIdx.x & 63;
    const int wid  = __builtin_amdgcn_readfirstlane(threadIdx.x >> 6);
    const int p0   = blockIdx.x * 128;

    for (int r = wid; r < 128; r += 4) {
        int pp = p0 + r;
        float v = 0.f;
        if (pp < EA) {
            const float* ap = (pp < NE) ? (eattr + (long)eidD[pp] * ED)
                                        : (loopa + (long)(pp - NE) * ED);
            v = ap[lane];
        }
        ea_lds[r][lane] = v;
    }
    __syncthreads();

    const int pA = p0 + lane;
    const int pB = p0 + 64 + lane;
    const bool vA = (pA < EA), vB = (pB < EA);
    int sA = 0, dA = 0, sB = 0, dB = 0;
    if (vA) { if (pA < NE) { sA = srcS[pA]; dA = dstS[pA]; } else { sA = dA = pA - NE; } }
    if (vB) { if (pB < NE) { sB = srcS[pB]; dB = dstS[pB]; } else { sB = dB = pB - NE; } }
    const int c0 = wid * CPW;

    float partA = 0.f, partB = 0.f;
    for (int ps = 0; ps < NPASS; ++ps) {
        const int cc = c0 + ps * 32;
        float accA[32], accB[32];
        #pragma unroll
        for (int j = 0; j < 32; ++j) { accA[j] = 0.f; accB[j] = 0.f; }
        for (int k = 0; k < 64; ++k) {
            float a1 = ea_lds[lane][k];
            float a2 = ea_lds[64 + lane][k];
            const float* wrow = we + (long)k * OC + cc;          // uniform -> s_load
            #pragma unroll
            for (int j = 0; j < 32; ++j) {
                float w = wrow[j];
                accA[j] = fmaf(a1, w, accA[j]);
                accB[j] = fmaf(a2, w, accB[j]);
            }
        }
        {
            const float4* xl4 = (const float4*)(xl + (long)sA * OC + cc);
            const float4* xr4 = (const float4*)(xr + (long)dA * OC + cc);
            #pragma unroll
            for (int j4 = 0; j4 < 8; ++j4) {
                float4 a4 = xl4[j4], b4 = xr4[j4];
                float m;
                m = accA[4*j4+0] + a4.x + b4.x; m = (m > 0.f) ? m : 0.2f * m; partA = fmaf(m, att[cc+4*j4+0], partA);
                m = accA[4*j4+1] + a4.y + b4.y; m = (m > 0.f) ? m : 0.2f * m; partA = fmaf(m, att[cc+4*j4+1], partA);
                m = accA[4*j4+2] + a4.z + b4.z; m = (m > 0.f) ? m : 0.2f * m; partA = fmaf(m, att[cc+4*j4+2], partA);
                m = accA[4*j4+3] + a4.w + b4.w; m = (m > 0.f) ? m : 0.2f * m; partA = fmaf(m, att[cc+4*j4+3], partA);
            }
        }
        {
            const float4* xl4 = (const float4*)(xl + (long)sB * OC + cc);
            const float4* xr4 = (const float4*)(xr + (long)dB * OC + cc);
            #pragma unroll
            for (int j4 = 0; j4 < 8; ++j4) {
                float4 a4 = xl4[j4], b4 = xr4[j4];
                float m;
                m = accB[4*j4+0] + a4.x + b4.x; m = (m > 0.f) ? m : 0.2f * m; partB = fmaf(m, att[cc+4*j4+0], partB);
                m = accB[4*j4+1] + a4.y + b4.y; m = (m > 0.f) ? m : 0.2f * m; partB = fmaf(m, att[cc+4*j4+1], partB);
                m = accB[4*j4+2] + a4.z + b4.z; m = (m > 0.f) ? m : 0.2f * m; partB = fmaf(m, att[cc+4*j4+2], partB);
                m = accB[4*j4+3] + a4.w + b4.w; m = (m > 0.f) ? m : 0.2f * m; partB = fmaf(m, att[cc+4*j4+3], partB);
            }
        }
    }
    p_lds[wid][lane]      = partA;
    p_lds[wid][64 + lane] = partB;
    __syncthreads();

    if (wid == 0) {
        if (vA) {
            if (HEADS == 2) {
                logits[(long)pA * 2 + 0] = p_lds[0][lane] + p_lds[1][lane];
                logits[(long)pA * 2 + 1] = p_lds[2][lane] + p_lds[3][lane];
            } else {
                logits[pA] = p_lds[0][lane] + p_lds[1][lane] + p_lds[2][lane] + p_lds[3][lane];
            }
        }
        if (vB) {
            if (HEADS == 2) {
                logits[(long)pB * 2 + 0] = p_lds[0][64 + lane] + p_lds[1][64 + lane];
                logits[(long)pB * 2 + 1] = p_lds[2][64 + lane] + p_lds[3][64 + lane];
            } else {
                logits[pB] = p_lds[0][64 + lane] + p_lds[1][64 + lane] + p_lds[2][64 + lane] + p_lds[3][64 + lane];
            }
        }
    }
}

// =====================================================================
// K5: fused segment softmax + aggregation + head-mean + LN + ELU.
//     ONE WAVE PER BLOCK (grid = NN).
// =====================================================================
template<int HEADS>
__global__ __launch_bounds__(64) void k_gat_reduce(
    const int* __restrict__ rpD, const int* __restrict__ srcS,
    const float* __restrict__ xl, const float* __restrict__ logits,
    const float* __restrict__ bias, const float* __restrict__ g, const float* __restrict__ b,
    float* __restrict__ hout)
{
    constexpr int OC = HEADS * 128;
    const int lane = threadIdx.x;
    const int n = blockIdx.x;

    const int base = rpD[n];
    const int deg  = rpD[n + 1] - base;
    const int c    = lane * 2;

    float m0 = -1e30f, m1 = -1e30f;
    for (int i = lane; i <= deg; i += 64) {
        long pp = (i < deg) ? (long)(base + i) : (long)(NE + n);
        if (HEADS == 2) {
            float2 lg = *(const float2*)&logits[pp * 2];
            m0 = fmaxf(m0, lg.x);
            m1 = fmaxf(m1, lg.y);
        } else {
            m0 = fmaxf(m0, logits[pp]);
        }
    }
    #pragma unroll
    for (int off = 32; off; off >>= 1) {
        m0 = fmaxf(m0, __shfl_xor(m0, off));
        if (HEADS == 2) m1 = fmaxf(m1, __shfl_xor(m1, off));
    }

    float s0 = 0.f, s1 = 0.f;
    for (int i = lane; i <= deg; i += 64) {
        long pp = (i < deg) ? (long)(base + i) : (long)(NE + n);
        if (HEADS == 2) {
            float2 lg = *(const float2*)&logits[pp * 2];
            s0 += __expf(lg.x - m0);
            s1 += __expf(lg.y - m1);
        } else {
            s0 += __expf(logits[pp] - m0);
        }
    }
    #pragma unroll
    for (int off = 32; off; off >>= 1) {
        s0 += __shfl_xor(s0, off);
        if (HEADS == 2) s1 += __shfl_xor(s1, off);
    }
    const float inv0 = 1.f / (s0 + 1e-16f);
    const float inv1 = 1.f / (s1 + 1e-16f);

    float a0 = 0.f, a1 = 0.f, a2 = 0.f, a3 = 0.f;
    float e0 = 0.f, e1 = 0.f, e2 = 0.f, e3 = 0.f;
    int i = 0;
    for (; i + 1 < deg; i += 2) {
        const long pA = base + i, pB = base + i + 1;
        const int  sA = __builtin_amdgcn_readfirstlane(srcS[pA]);
        const int  sB = __builtin_amdgcn_readfirstlane(srcS[pB]);
        const float* xrA = xl + (long)sA * OC;
        const float* xrB = xl + (long)sB * OC;
        if (HEADS == 2) {
            float2 lgA = *(const float2*)&logits[pA * 2];
            float2 lgB = *(const float2*)&logits[pB * 2];
            const float wA0 = __expf(lgA.x - m0) * inv0;
            const float wA1 = __expf(lgA.y - m1) * inv1;
            const float wB0 = __expf(lgB.x - m0) * inv0;
            const float wB1 = __expf(lgB.y - m1) * inv1;
            float2 xA0 = *(const float2*)(xrA + c);
            float2 xA1 = *(const float2*)(xrA + 128 + c);
            float2 xB0 = *(const float2*)(xrB + c);
            float2 xB1 = *(const float2*)(xrB + 128 + c);
            a0 = fmaf(xA0.x, wA0, a0);  a1 = fmaf(xA0.y, wA0, a1);
            a2 = fmaf(xA1.x, wA1, a2);  a3 = fmaf(xA1.y, wA1, a3);
            e0 = fmaf(xB0.x, wB0, e0);  e1 = fmaf(xB0.y, wB0, e1);
            e2 = fmaf(xB1.x, wB1, e2);  e3 = fmaf(xB1.y, wB1, e3);
        } else {
            const float wA0 = __expf(logits[pA] - m0) * inv0;
            const float wB0 = __expf(logits[pB] - m0) * inv0;
            float2 xA0 = *(const float2*)(xrA + c);
            float2 xB0 = *(const float2*)(xrB + c);
            a0 = fmaf(xA0.x, wA0, a0);  a1 = fmaf(xA0.y, wA0, a1);
            e0 = fmaf(xB0.x, wB0, e0);  e1 = fmaf(xB0.y, wB0, e1);
        }
    }
    for (; i <= deg; ++i) {                               // tail + self loop
        const bool selfE = (i == deg);
        const long pp = selfE ? (long)(NE + n) : (long)(base + i);
        const int  sN = __builtin_amdgcn_readfirstlane(selfE ? n : srcS[base + i]);
        const float* xrow = xl + (long)sN * OC;
        if (HEADS == 2) {
            float2 lg = *(const float2*)&logits[pp * 2];
            const float w0 = __expf(lg.x - m0) * inv0;
            const float w1 = __expf(lg.y - m1) * inv1;
            float2 x0 = *(const float2*)(xrow + c);
            float2 x1 = *(const float2*)(xrow + 128 + c);
            a0 = fmaf(x0.x, w0, a0);  a1 = fmaf(x0.y, w0, a1);
            a2 = fmaf(x1.x, w1, a2);  a3 = fmaf(x1.y, w1, a3);
        } else {
            const float w0 = __expf(logits[pp] - m0) * inv0;
            float2 x0 = *(const float2*)(xrow + c);
            a0 = fmaf(x0.x, w0, a0);  a1 = fmaf(x0.y, w0, a1);
        }
    }
    a0 += e0; a1 += e1; a2 += e2; a3 += e3;

    float v0, v1;
    if (HEADS == 2) { v0 = 0.5f * (a0 + a2); v1 = 0.5f * (a1 + a3); }
    else            { v0 = a0;               v1 = a1; }
    float2 bb = *(const float2*)&bias[c];
    v0 += bb.x;
    v1 += bb.y;

    float sum = v0 + v1;
    #pragma unroll
    for (int off = 32; off; off >>= 1) sum += __shfl_xor(sum, off);
    const float mu = sum * (1.f / 128.f);
    const float q0 = v0 - mu, q1 = v1 - mu;
    float vs = q0 * q0 + q1 * q1;
    #pragma unroll
    for (int off = 32; off; off >>= 1) vs += __shfl_xor(vs, off);
    const float rstd = rsqrtf(vs * (1.f / 128.f) + 1e-5f);

    float2 gg = *(const float2*)&g[c];
    float2 bv = *(const float2*)&b[c];
    float y0 = q0 * rstd * gg.x + bv.x;
    float y1 = q1 * rstd * gg.y + bv.y;
    float2 outv;
    outv.x = (y0 > 0.f) ? y0 : (__expf(y0) - 1.f);
    outv.y = (y1 > 0.f) ? y1 : (__expf(y1) - 1.f);
    *(float2*)&hout[(long)n * 128 + c] = outv;
}

// =====================================================================
// K8: classifier over dst-sorted edges (Pd reads cached); scatter out.
// =====================================================================
__global__ __launch_bounds__(256) void k_classifier(
    const float* __restrict__ Ps, const float* __restrict__ Pd,
    const int* __restrict__ eidD, const int* __restrict__ srcS, const int* __restrict__ dstS,
    const float* __restrict__ eattr,
    const float* __restrict__ c1we, const float* __restrict__ c1b,
    const float* __restrict__ c2w, const float* __restrict__ c2b,
    const float* __restrict__ c3w, const float* __restrict__ c3b,
    float* __restrict__ out)
{
    __shared__ float smem[128 * 65];     // phase1: ea [64][65]; phase2: z1^T [128][65]
    __shared__ float p_lds[4][64];
    const int lane = threadIdx.x & 63;
    const int wid  = __builtin_amdgcn_readfirstlane(threadIdx.x >> 6);
    const int p0   = blockIdx.x * 64;
    const int p    = p0 + lane;
    const bool val = (p < NE);
    const int c0   = wid * 32;

    for (int rr = wid; rr < 64; rr += 4) {
        int pp = p0 + rr;
        smem[rr * 65 + lane] = (pp < NE) ? eattr[(long)eidD[pp] * ED + lane] : 0.f;
    }
    __syncthreads();

    float acc[32];
    #pragma unroll
    for (int j = 0; j < 32; ++j) acc[j] = c1b[c0 + j];
    for (int k = 0; k < 64; ++k) {
        float a = smem[lane * 65 + k];
        const float* wrow = c1we + (long)k * 128 + c0;
        #pragma unroll
        for (int j = 0; j < 32; ++j) acc[j] = fmaf(a, wrow[j], acc[j]);
    }

    const int sN = val ? srcS[p] : 0;
    const int dN = val ? dstS[p] : 0;
    const float4* ps4 = (const float4*)(Ps + (long)sN * 128 + c0);
    const float4* pd4 = (const float4*)(Pd + (long)dN * 128 + c0);  // ~same row across wave
    #pragma unroll
    for (int j4 = 0; j4 < 8; ++j4) {
        float4 a4 = ps4[j4], b4 = pd4[j4];
        acc[4*j4+0] += a4.x + b4.x;
        acc[4*j4+1] += a4.y + b4.y;
        acc[4*j4+2] += a4.z + b4.z;
        acc[4*j4+3] += a4.w + b4.w;
    }

    __syncthreads();
    #pragma unroll
    for (int j = 0; j < 32; ++j) smem[(c0 + j) * 65 + lane] = fmaxf(acc[j], 0.f);  // z1^T
    __syncthreads();

    float acc2[16];
    #pragma unroll
    for (int j = 0; j < 16; ++j) acc2[j] = c2b[wid * 16 + j];
    for (int k = 0; k < 128; ++k) {
        float a = smem[k * 65 + lane];
        const float* wrow = c2w + (long)k * 64 + wid * 16;
        #pragma unroll
        for (int j = 0; j < 16; ++j) acc2[j] = fmaf(a, wrow[j], acc2[j]);
    }
    float part = 0.f;
    #pragma unroll
    for (int j = 0; j < 16; ++j) part = fmaf(fmaxf(acc2[j], 0.f), c3w[wid * 16 + j], part);
    p_lds[wid][lane] = part;
    __syncthreads();
    if (wid == 0 && val)
        out[eidD[p]] = p_lds[0][lane] + p_lds[1][lane] + p_lds[2][lane] + p_lds[3][lane] + c3b[0];
}

// =====================================================================
extern "C" void kernel_launch(void* const* d_in, const int* in_sizes, int n_in,
                              void* d_out, int out_size, void* d_ws, size_t ws_size,
                              hipStream_t stream)
{
    const int*   edge_index = (const int*)  d_in[1];
    const float* edge_attr  = (const float*)d_in[2];
    const float* ep_w  = (const float*)d_in[3];
    const float* ep_b  = (const float*)d_in[4];
    const float* g1_wl = (const float*)d_in[5];
    const float* g1_wr = (const float*)d_in[6];
    const float* g1_we = (const float*)d_in[7];
    const float* g1_att= (const float*)d_in[8];
    const float* g1_b  = (const float*)d_in[9];
    const float* n1_g  = (const float*)d_in[10];
    const float* n1_b  = (const float*)d_in[11];
    const float* g2_wl = (const float*)d_in[12];
    const float* g2_wr = (const float*)d_in[13];
    const float* g2_we = (const float*)d_in[14];
    const float* g2_att= (const float*)d_in[15];
    const float* g2_b  = (const float*)d_in[16];
    const float* n2_g  = (const float*)d_in[17];
    const float* n2_b  = (const float*)d_in[18];
    const float* c1_w  = (const float*)d_in[19];
    const float* c1_b  = (const float*)d_in[20];
    const float* c2_w  = (const float*)d_in[21];
    const float* c2_b  = (const float*)d_in[22];
    const float* c3_w  = (const float*)d_in[23];
    const float* c3_b  = (const float*)d_in[24];
    const int* src = edge_index;
    const int* dst = edge_index + NE;

    // ---- workspace layout ----
    char* wsb = (char*)d_ws;
    size_t o = 0;
    auto alloc = [&](size_t bytes) { void* p = wsb + o; o += (bytes + 255) & ~(size_t)255; return p; };
    int* cntS = (int*)alloc(NN * 4);          // cntS+cntD must stay first (one memset)
    int* cntD = (int*)alloc(NN * 4);
    int* curS = (int*)alloc(NN * 4);
    int* curD = (int*)alloc(NN * 4);
    int* rpS  = (int*)alloc((NN + 1) * 4);
    int* rpD  = (int*)alloc((NN + 1) * 4);
    int* eidS = (int*)alloc((size_t)NE * 4);
    int* eidD = (int*)alloc((size_t)NE * 4);
    int* srcS = (int*)alloc((size_t)NE * 4);
    int* dstS = (int*)alloc((size_t)NE * 4);
    float* loopa   = (float*)alloc((size_t)NN * 64 * 4);
    float* x_input = (float*)alloc((size_t)NN * 256 * 4);   // reused: h2
    float* xl1     = (float*)alloc((size_t)NN * 256 * 4);   // reused: xl2, Ps
    float* xr1     = (float*)alloc((size_t)NN * 256 * 4);   // reused: xr2, Pd
    float* logits  = (float*)alloc((size_t)EA * 2 * 4);
    float* h1      = (float*)alloc((size_t)NN * 128 * 4);
    float* xl2 = xl1;
    float* xr2 = xr1;
    float* h2  = x_input;
    float* Ps  = xl1;
    float* Pd  = xr1;

    // ---- CSR build ----
    hipMemsetAsync(d_ws, 0, 2 * ((NN * 4 + 255) & ~255), stream);   // cntS + cntD
    k_hist<<<(NE + 255) / 256, 256, 0, stream>>>(src, dst, cntS, cntD);
    k_scan<<<1, 1024, 0, stream>>>(cntS, cntD, rpS, rpD, curS, curD);
    k_scatter<<<(NE + 255) / 256, 256, 0, stream>>>(src, dst, curS, curD, eidS, eidD, srcS, dstS);

    // ---- stage 1: node input features, src pass then dst pass ----
    k_node_src<<<NN, 64, 0, stream>>>(edge_attr, rpS, eidS, ep_w, ep_b, x_input);
    k_node_dst<<<NN, 64, 0, stream>>>(edge_attr, rpD, eidD, ep_w, ep_b, x_input, loopa);

    // ---- GAT layer 1 (heads=2) ----
    k_gemm2<256, 256><<<(NN + 63) / 64, 512, 0, stream>>>(x_input, g1_wl, g1_wr, xl1, xr1, NN);
    k_gat_logits<2><<<(EA + 127) / 128, 256, 0, stream>>>(edge_attr, eidD, srcS, dstS, loopa,
                                                          xl1, xr1, g1_we, g1_att, logits);
    k_gat_reduce<2><<<NN, 64, 0, stream>>>(rpD, srcS, xl1, logits, g1_b, n1_g, n1_b, h1);

    // ---- GAT layer 2 (heads=1) ----
    k_gemm2<128, 128><<<(NN + 63) / 64, 512, 0, stream>>>(h1, g2_wl, g2_wr, xl2, xr2, NN);
    k_gat_logits<1><<<(EA + 127) / 128, 256, 0, stream>>>(edge_attr, eidD, srcS, dstS, loopa,
                                                          xl2, xr2, g2_we, g2_att, logits);
    k_gat_reduce<1><<<NN, 64, 0, stream>>>(rpD, srcS, xl2, logits, g2_b, n2_g, n2_b, h2);

    // ---- classifier: node-decomposed layer 1, dst-sorted traversal ----
    k_gemm2<128, 128><<<(NN + 63) / 64, 512, 0, stream>>>(h2, c1_w, c1_w + 128 * 128, Ps, Pd, NN);
    k_classifier<<<(NE + 63) / 64, 256, 0, stream>>>(Ps, Pd, eidD, srcS, dstS, edge_attr,
                                                     c1_w + 256 * 128, c1_b, c2_w, c2_b, c3_w, c3_b,
                                                     (float*)d_out);
}

// Round 17
// 2011.530 us; speedup vs baseline: 1.0130x; 1.0130x over previous
//
#include <hip/hip_runtime.h>

// ---- problem constants ----
constexpr int   NN  = 50000;            // nodes
constexpr int   NE  = 600000;           // edges
constexpr int   EA  = NE + NN;          // augmented edges (self loops appended)
constexpr int   ND  = 128;              // node dim
constexpr int   ED  = 64;               // edge dim
constexpr int   HD  = 128;              // hidden dim

// =====================================================================
// CSR build: histogram -> prefix scan -> scatter (+ sorted src/dst)
// =====================================================================
__global__ void k_hist(const int* __restrict__ src, const int* __restrict__ dst,
                       int* __restrict__ cntS, int* __restrict__ cntD)
{
    int e = blockIdx.x * 256 + threadIdx.x;
    if (e >= NE) return;
    atomicAdd(&cntS[src[e]], 1);
    atomicAdd(&cntD[dst[e]], 1);
}

__global__ __launch_bounds__(1024) void k_scan(
    const int* __restrict__ cntS, const int* __restrict__ cntD,
    int* __restrict__ rpS, int* __restrict__ rpD,
    int* __restrict__ curS, int* __restrict__ curD)
{
    __shared__ int part[1024];
    const int tid = threadIdx.x;
    constexpr int CH = (NN + 1023) / 1024;
    for (int pass = 0; pass < 2; ++pass) {
        const int* cnt = pass ? cntD : cntS;
        int* rp  = pass ? rpD  : rpS;
        int* cur = pass ? curD : curS;
        int i0 = tid * CH, i1 = (i0 + CH < NN) ? i0 + CH : NN;
        int ls = 0;
        for (int i = i0; i < i1; ++i) ls += cnt[i];
        part[tid] = ls;
        __syncthreads();
        for (int off = 1; off < 1024; off <<= 1) {
            int v = (tid >= off) ? part[tid - off] : 0;
            __syncthreads();
            part[tid] += v;
            __syncthreads();
        }
        int run = tid ? part[tid - 1] : 0;
        for (int i = i0; i < i1; ++i) { rp[i] = run; cur[i] = run; run += cnt[i]; }
        if (tid == 1023) rp[NN] = run;
        __syncthreads();
    }
}

__global__ void k_scatter(const int* __restrict__ src, const int* __restrict__ dst,
                          int* __restrict__ curS, int* __restrict__ curD,
                          int* __restrict__ eidS, int* __restrict__ eidD,
                          int* __restrict__ srcS, int* __restrict__ dstS)
{
    int e = blockIdx.x * 256 + threadIdx.x;
    if (e >= NE) return;
    int s = src[e], d = dst[e];
    eidS[atomicAdd(&curS[s], 1)] = e;
    int pd = atomicAdd(&curD[d], 1);
    eidD[pd] = e;
    srcS[pd] = s;
    dstS[pd] = d;
}

// =====================================================================
// K1: node-centric edge-projection means. r15-exact version (measured
//     442us): one wave per node, r5 inner shape. (r16's src/dst split
//     + adjacent-col float2 regressed; reverted.)
// =====================================================================
__global__ __launch_bounds__(64) void k_node_inputs(
    const float* __restrict__ eattr,
    const int* __restrict__ rpS, const int* __restrict__ eidS,
    const int* __restrict__ rpD, const int* __restrict__ eidD,
    const float* __restrict__ ep_w, const float* __restrict__ ep_b,
    float* __restrict__ x_input, float* __restrict__ loopa)
{
    const int lane = threadIdx.x;
    const int n = blockIdx.x;

    float w0r[64], w1r[64];
    #pragma unroll
    for (int k = 0; k < 64; ++k) {
        w0r[k] = ep_w[k * ND + lane];
        w1r[k] = ep_w[k * ND + 64 + lane];
    }
    const float bb0 = ep_b[lane], bb1 = ep_b[64 + lane];

    float aO0 = 0.f, aO1 = 0.f;
    const int s0 = rpS[n], s1 = rpS[n + 1];
    for (int i = s0; i < s1; ++i) {
        const int e = __builtin_amdgcn_readfirstlane(eidS[i]);
        const float* ea = eattr + (long)e * ED;
        float d0 = bb0, d1 = bb1;
        #pragma unroll
        for (int k = 0; k < 64; ++k) {
            float a = ea[k];                       // uniform -> s_load
            d0 = fmaf(a, w0r[k], d0);
            d1 = fmaf(a, w1r[k], d1);
        }
        aO0 += fmaxf(d0, 0.f);
        aO1 += fmaxf(d1, 0.f);
    }

    float aI0 = 0.f, aI1 = 0.f, la = 0.f;
    const int d0i = rpD[n], d1i = rpD[n + 1];
    for (int i = d0i; i < d1i; ++i) {
        const int e = __builtin_amdgcn_readfirstlane(eidD[i]);
        const float* ea = eattr + (long)e * ED;
        la += ea[lane];
        float d0 = bb0, d1 = bb1;
        #pragma unroll
        for (int k = 0; k < 64; ++k) {
            float a = ea[k];
            d0 = fmaf(a, w0r[k], d0);
            d1 = fmaf(a, w1r[k], d1);
        }
        aI0 += fmaxf(d0, 0.f);
        aI1 += fmaxf(d1, 0.f);
    }

    const float invS = 1.f / (float)((s1 - s0) > 1 ? (s1 - s0) : 1);
    const float invD = 1.f / (float)((d1i - d0i) > 1 ? (d1i - d0i) : 1);
    float* xrow = x_input + (long)n * 256;
    xrow[lane]        = aO0 * invS;
    xrow[64 + lane]   = aO1 * invS;
    xrow[128 + lane]  = aI0 * invD;
    xrow[192 + lane]  = aI1 * invD;
    loopa[(long)n * ED + lane] = la * invD;
}

// =====================================================================
// K3: dual-output dense GEMM -- C1 = A@W1, C2 = A@W2 (shared A staging).
// =====================================================================
template<int KD, int NC>
__global__ __launch_bounds__(512) void k_gemm2(const float* __restrict__ A,
                                               const float* __restrict__ W1,
                                               const float* __restrict__ W2,
                                               float* __restrict__ C1,
                                               float* __restrict__ C2, int M)
{
    constexpr int CPW = NC / 8;                    // 32 (NC=256) / 16 (NC=128)
    __shared__ float a_lds[64][65];
    const int lane = threadIdx.x & 63;
    const int wid  = __builtin_amdgcn_readfirstlane(threadIdx.x >> 6);   // 0..7
    const int r0   = blockIdx.x * 64;
    const int row  = r0 + lane;

    float acc1[CPW], acc2[CPW];
    #pragma unroll
    for (int j = 0; j < CPW; ++j) { acc1[j] = 0.f; acc2[j] = 0.f; }

    for (int k0 = 0; k0 < KD; k0 += 64) {
        __syncthreads();
        for (int r = wid; r < 64; r += 8) {
            int rr = r0 + r;
            a_lds[r][lane] = (rr < M) ? A[(long)rr * KD + k0 + lane] : 0.f;
        }
        __syncthreads();
        for (int k = 0; k < 64; ++k) {
            float a = a_lds[lane][k];
            const float* w1row = W1 + (long)(k0 + k) * NC + wid * CPW;
            const float* w2row = W2 + (long)(k0 + k) * NC + wid * CPW;
            #pragma unroll
            for (int j = 0; j < CPW; ++j) {
                acc1[j] = fmaf(a, w1row[j], acc1[j]);
                acc2[j] = fmaf(a, w2row[j], acc2[j]);
            }
        }
    }
    if (row < M) {
        float* c1row = C1 + (long)row * NC + wid * CPW;
        float* c2row = C2 + (long)row * NC + wid * CPW;
        #pragma unroll
        for (int j = 0; j < CPW; ++j) { c1row[j] = acc1[j]; c2row[j] = acc2[j]; }
    }
}

// =====================================================================
// K4: edge-parallel logits, 2 positions per lane (register blocking).
//     Gather indices (srcS/dstS) loaded BEFORE ea staging so their
//     latency hides under the staging barrier.
// =====================================================================
template<int HEADS>
__global__ __launch_bounds__(256) void k_gat_logits(
    const float* __restrict__ eattr,
    const int* __restrict__ eidD, const int* __restrict__ srcS, const int* __restrict__ dstS,
    const float* __restrict__ loopa,
    const float* __restrict__ xl, const float* __restrict__ xr,
    const float* __restrict__ we, const float* __restrict__ att,
    float* __restrict__ logits)
{
    constexpr int OC    = HEADS * 128;
    constexpr int CPW   = OC / 4;                  // 64 (H=2) / 32 (H=1)
    constexpr int NPASS = CPW / 32;                // 2 / 1
    __shared__ float ea_lds[128][65];
    __shared__ float p_lds[4][128];
    const int lane = threadIdx.x & 63;
    const int wid  = __builtin_amdgcn_readfirstlane(threadIdx.x >> 6);
    const int p0   = blockIdx.x * 128;

    // issue index loads first (latency hidden under ea staging)
    const int pA = p0 + lane;
    const int pB = p0 + 64 + lane;
    const bool vA = (pA < EA), vB = (pB < EA);
    int sA = 0, dA = 0, sB = 0, dB = 0;
    if (vA) { if (pA < NE) { sA = srcS[pA]; dA = dstS[pA]; } else { sA = dA = pA - NE; } }
    if (vB) { if (pB < NE) { sB = srcS[pB]; dB = dstS[pB]; } else { sB = dB = pB - NE; } }

    for (int r = wid; r < 128; r += 4) {
        int pp = p0 + r;
        float v = 0.f;
        if (pp < EA) {
            const float* ap = (pp < NE) ? (eattr + (long)eidD[pp] * ED)
                                        : (loopa + (long)(pp - NE) * ED);
            v = ap[lane];
        }
        ea_lds[r][lane] = v;
    }
    __syncthreads();

    const int c0 = wid * CPW;

    float partA = 0.f, partB = 0.f;
    for (int ps = 0; ps < NPASS; ++ps) {
        const int cc = c0 + ps * 32;
        float accA[32], accB[32];
        #pragma unroll
        for (int j = 0; j < 32; ++j) { accA[j] = 0.f; accB[j] = 0.f; }
        for (int k = 0; k < 64; ++k) {
            float a1 = ea_lds[lane][k];
            float a2 = ea_lds[64 + lane][k];
            const float* wrow = we + (long)k * OC + cc;          // uniform -> s_load
            #pragma unroll
            for (int j = 0; j < 32; ++j) {
                float w = wrow[j];
                accA[j] = fmaf(a1, w, accA[j]);
                accB[j] = fmaf(a2, w, accB[j]);
            }
        }
        {
            const float4* xl4 = (const float4*)(xl + (long)sA * OC + cc);
            const float4* xr4 = (const float4*)(xr + (long)dA * OC + cc);
            #pragma unroll
            for (int j4 = 0; j4 < 8; ++j4) {
                float4 a4 = xl4[j4], b4 = xr4[j4];
                float m;
                m = accA[4*j4+0] + a4.x + b4.x; m = (m > 0.f) ? m : 0.2f * m; partA = fmaf(m, att[cc+4*j4+0], partA);
                m = accA[4*j4+1] + a4.y + b4.y; m = (m > 0.f) ? m : 0.2f * m; partA = fmaf(m, att[cc+4*j4+1], partA);
                m = accA[4*j4+2] + a4.z + b4.z; m = (m > 0.f) ? m : 0.2f * m; partA = fmaf(m, att[cc+4*j4+2], partA);
                m = accA[4*j4+3] + a4.w + b4.w; m = (m > 0.f) ? m : 0.2f * m; partA = fmaf(m, att[cc+4*j4+3], partA);
            }
        }
        {
            const float4* xl4 = (const float4*)(xl + (long)sB * OC + cc);
            const float4* xr4 = (const float4*)(xr + (long)dB * OC + cc);
            #pragma unroll
            for (int j4 = 0; j4 < 8; ++j4) {
                float4 a4 = xl4[j4], b4 = xr4[j4];
                float m;
                m = accB[4*j4+0] + a4.x + b4.x; m = (m > 0.f) ? m : 0.2f * m; partB = fmaf(m, att[cc+4*j4+0], partB);
                m = accB[4*j4+1] + a4.y + b4.y; m = (m > 0.f) ? m : 0.2f * m; partB = fmaf(m, att[cc+4*j4+1], partB);
                m = accB[4*j4+2] + a4.z + b4.z; m = (m > 0.f) ? m : 0.2f * m; partB = fmaf(m, att[cc+4*j4+2], partB);
                m = accB[4*j4+3] + a4.w + b4.w; m = (m > 0.f) ? m : 0.2f * m; partB = fmaf(m, att[cc+4*j4+3], partB);
            }
        }
    }
    p_lds[wid][lane]      = partA;
    p_lds[wid][64 + lane] = partB;
    __syncthreads();

    if (wid == 0) {
        if (vA) {
            if (HEADS == 2) {
                logits[(long)pA * 2 + 0] = p_lds[0][lane] + p_lds[1][lane];
                logits[(long)pA * 2 + 1] = p_lds[2][lane] + p_lds[3][lane];
            } else {
                logits[pA] = p_lds[0][lane] + p_lds[1][lane] + p_lds[2][lane] + p_lds[3][lane];
            }
        }
        if (vB) {
            if (HEADS == 2) {
                logits[(long)pB * 2 + 0] = p_lds[0][64 + lane] + p_lds[1][64 + lane];
                logits[(long)pB * 2 + 1] = p_lds[2][64 + lane] + p_lds[3][64 + lane];
            } else {
                logits[pB] = p_lds[0][64 + lane] + p_lds[1][64 + lane] + p_lds[2][64 + lane] + p_lds[3][64 + lane];
            }
        }
    }
}

// =====================================================================
// K5: fused segment softmax + aggregation + head-mean + LN + ELU.
//     ONE WAVE PER BLOCK (grid = NN).
// =====================================================================
template<int HEADS>
__global__ __launch_bounds__(64) void k_gat_reduce(
    const int* __restrict__ rpD, const int* __restrict__ srcS,
    const float* __restrict__ xl, const float* __restrict__ logits,
    const float* __restrict__ bias, const float* __restrict__ g, const float* __restrict__ b,
    float* __restrict__ hout)
{
    constexpr int OC = HEADS * 128;
    const int lane = threadIdx.x;
    const int n = blockIdx.x;

    const int base = rpD[n];
    const int deg  = rpD[n + 1] - base;
    const int c    = lane * 2;

    float m0 = -1e30f, m1 = -1e30f;
    for (int i = lane; i <= deg; i += 64) {
        long pp = (i < deg) ? (long)(base + i) : (long)(NE + n);
        if (HEADS == 2) {
            float2 lg = *(const float2*)&logits[pp * 2];
            m0 = fmaxf(m0, lg.x);
            m1 = fmaxf(m1, lg.y);
        } else {
            m0 = fmaxf(m0, logits[pp]);
        }
    }
    #pragma unroll
    for (int off = 32; off; off >>= 1) {
        m0 = fmaxf(m0, __shfl_xor(m0, off));
        if (HEADS == 2) m1 = fmaxf(m1, __shfl_xor(m1, off));
    }

    float s0 = 0.f, s1 = 0.f;
    for (int i = lane; i <= deg; i += 64) {
        long pp = (i < deg) ? (long)(base + i) : (long)(NE + n);
        if (HEADS == 2) {
            float2 lg = *(const float2*)&logits[pp * 2];
            s0 += __expf(lg.x - m0);
            s1 += __expf(lg.y - m1);
        } else {
            s0 += __expf(logits[pp] - m0);
        }
    }
    #pragma unroll
    for (int off = 32; off; off >>= 1) {
        s0 += __shfl_xor(s0, off);
        if (HEADS == 2) s1 += __shfl_xor(s1, off);
    }
    const float inv0 = 1.f / (s0 + 1e-16f);
    const float inv1 = 1.f / (s1 + 1e-16f);

    float a0 = 0.f, a1 = 0.f, a2 = 0.f, a3 = 0.f;
    float e0 = 0.f, e1 = 0.f, e2 = 0.f, e3 = 0.f;
    int i = 0;
    for (; i + 1 < deg; i += 2) {
        const long pA = base + i, pB = base + i + 1;
        const int  sA = __builtin_amdgcn_readfirstlane(srcS[pA]);
        const int  sB = __builtin_amdgcn_readfirstlane(srcS[pB]);
        const float* xrA = xl + (long)sA * OC;
        const float* xrB = xl + (long)sB * OC;
        if (HEADS == 2) {
            float2 lgA = *(const float2*)&logits[pA * 2];
            float2 lgB = *(const float2*)&logits[pB * 2];
            const float wA0 = __expf(lgA.x - m0) * inv0;
            const float wA1 = __expf(lgA.y - m1) * inv1;
            const float wB0 = __expf(lgB.x - m0) * inv0;
            const float wB1 = __expf(lgB.y - m1) * inv1;
            float2 xA0 = *(const float2*)(xrA + c);
            float2 xA1 = *(const float2*)(xrA + 128 + c);
            float2 xB0 = *(const float2*)(xrB + c);
            float2 xB1 = *(const float2*)(xrB + 128 + c);
            a0 = fmaf(xA0.x, wA0, a0);  a1 = fmaf(xA0.y, wA0, a1);
            a2 = fmaf(xA1.x, wA1, a2);  a3 = fmaf(xA1.y, wA1, a3);
            e0 = fmaf(xB0.x, wB0, e0);  e1 = fmaf(xB0.y, wB0, e1);
            e2 = fmaf(xB1.x, wB1, e2);  e3 = fmaf(xB1.y, wB1, e3);
        } else {
            const float wA0 = __expf(logits[pA] - m0) * inv0;
            const float wB0 = __expf(logits[pB] - m0) * inv0;
            float2 xA0 = *(const float2*)(xrA + c);
            float2 xB0 = *(const float2*)(xrB + c);
            a0 = fmaf(xA0.x, wA0, a0);  a1 = fmaf(xA0.y, wA0, a1);
            e0 = fmaf(xB0.x, wB0, e0);  e1 = fmaf(xB0.y, wB0, e1);
        }
    }
    for (; i <= deg; ++i) {                               // tail + self loop
        const bool selfE = (i == deg);
        const long pp = selfE ? (long)(NE + n) : (long)(base + i);
        const int  sN = __builtin_amdgcn_readfirstlane(selfE ? n : srcS[base + i]);
        const float* xrow = xl + (long)sN * OC;
        if (HEADS == 2) {
            float2 lg = *(const float2*)&logits[pp * 2];
            const float w0 = __expf(lg.x - m0) * inv0;
            const float w1 = __expf(lg.y - m1) * inv1;
            float2 x0 = *(const float2*)(xrow + c);
            float2 x1 = *(const float2*)(xrow + 128 + c);
            a0 = fmaf(x0.x, w0, a0);  a1 = fmaf(x0.y, w0, a1);
            a2 = fmaf(x1.x, w1, a2);  a3 = fmaf(x1.y, w1, a3);
        } else {
            const float w0 = __expf(logits[pp] - m0) * inv0;
            float2 x0 = *(const float2*)(xrow + c);
            a0 = fmaf(x0.x, w0, a0);  a1 = fmaf(x0.y, w0, a1);
        }
    }
    a0 += e0; a1 += e1; a2 += e2; a3 += e3;

    float v0, v1;
    if (HEADS == 2) { v0 = 0.5f * (a0 + a2); v1 = 0.5f * (a1 + a3); }
    else            { v0 = a0;               v1 = a1; }
    float2 bb = *(const float2*)&bias[c];
    v0 += bb.x;
    v1 += bb.y;

    float sum = v0 + v1;
    #pragma unroll
    for (int off = 32; off; off >>= 1) sum += __shfl_xor(sum, off);
    const float mu = sum * (1.f / 128.f);
    const float q0 = v0 - mu, q1 = v1 - mu;
    float vs = q0 * q0 + q1 * q1;
    #pragma unroll
    for (int off = 32; off; off >>= 1) vs += __shfl_xor(vs, off);
    const float rstd = rsqrtf(vs * (1.f / 128.f) + 1e-5f);

    float2 gg = *(const float2*)&g[c];
    float2 bv = *(const float2*)&b[c];
    float y0 = q0 * rstd * gg.x + bv.x;
    float y1 = q1 * rstd * gg.y + bv.y;
    float2 outv;
    outv.x = (y0 > 0.f) ? y0 : (__expf(y0) - 1.f);
    outv.y = (y1 > 0.f) ? y1 : (__expf(y1) - 1.f);
    *(float2*)&hout[(long)n * 128 + c] = outv;
}

// =====================================================================
// K8: classifier over dst-sorted edges (Pd reads cached); scatter out.
// =====================================================================
__global__ __launch_bounds__(256) void k_classifier(
    const float* __restrict__ Ps, const float* __restrict__ Pd,
    const int* __restrict__ eidD, const int* __restrict__ srcS, const int* __restrict__ dstS,
    const float* __restrict__ eattr,
    const float* __restrict__ c1we, const float* __restrict__ c1b,
    const float* __restrict__ c2w, const float* __restrict__ c2b,
    const float* __restrict__ c3w, const float* __restrict__ c3b,
    float* __restrict__ out)
{
    __shared__ float smem[128 * 65];     // phase1: ea [64][65]; phase2: z1^T [128][65]
    __shared__ float p_lds[4][64];
    const int lane = threadIdx.x & 63;
    const int wid  = __builtin_amdgcn_readfirstlane(threadIdx.x >> 6);
    const int p0   = blockIdx.x * 64;
    const int p    = p0 + lane;
    const bool val = (p < NE);
    const int c0   = wid * 32;

    for (int rr = wid; rr < 64; rr += 4) {
        int pp = p0 + rr;
        smem[rr * 65 + lane] = (pp < NE) ? eattr[(long)eidD[pp] * ED + lane] : 0.f;
    }
    __syncthreads();

    float acc[32];
    #pragma unroll
    for (int j = 0; j < 32; ++j) acc[j] = c1b[c0 + j];
    for (int k = 0; k < 64; ++k) {
        float a = smem[lane * 65 + k];
        const float* wrow = c1we + (long)k * 128 + c0;
        #pragma unroll
        for (int j = 0; j < 32; ++j) acc[j] = fmaf(a, wrow[j], acc[j]);
    }

    const int sN = val ? srcS[p] : 0;
    const int dN = val ? dstS[p] : 0;
    const float4* ps4 = (const float4*)(Ps + (long)sN * 128 + c0);
    const float4* pd4 = (const float4*)(Pd + (long)dN * 128 + c0);  // ~same row across wave
    #pragma unroll
    for (int j4 = 0; j4 < 8; ++j4) {
        float4 a4 = ps4[j4], b4 = pd4[j4];
        acc[4*j4+0] += a4.x + b4.x;
        acc[4*j4+1] += a4.y + b4.y;
        acc[4*j4+2] += a4.z + b4.z;
        acc[4*j4+3] += a4.w + b4.w;
    }

    __syncthreads();
    #pragma unroll
    for (int j = 0; j < 32; ++j) smem[(c0 + j) * 65 + lane] = fmaxf(acc[j], 0.f);  // z1^T
    __syncthreads();

    float acc2[16];
    #pragma unroll
    for (int j = 0; j < 16; ++j) acc2[j] = c2b[wid * 16 + j];
    for (int k = 0; k < 128; ++k) {
        float a = smem[k * 65 + lane];
        const float* wrow = c2w + (long)k * 64 + wid * 16;
        #pragma unroll
        for (int j = 0; j < 16; ++j) acc2[j] = fmaf(a, wrow[j], acc2[j]);
    }
    float part = 0.f;
    #pragma unroll
    for (int j = 0; j < 16; ++j) part = fmaf(fmaxf(acc2[j], 0.f), c3w[wid * 16 + j], part);
    p_lds[wid][lane] = part;
    __syncthreads();
    if (wid == 0 && val)
        out[eidD[p]] = p_lds[0][lane] + p_lds[1][lane] + p_lds[2][lane] + p_lds[3][lane] + c3b[0];
}

// =====================================================================
extern "C" void kernel_launch(void* const* d_in, const int* in_sizes, int n_in,
                              void* d_out, int out_size, void* d_ws, size_t ws_size,
                              hipStream_t stream)
{
    const int*   edge_index = (const int*)  d_in[1];
    const float* edge_attr  = (const float*)d_in[2];
    const float* ep_w  = (const float*)d_in[3];
    const float* ep_b  = (const float*)d_in[4];
    const float* g1_wl = (const float*)d_in[5];
    const float* g1_wr = (const float*)d_in[6];
    const float* g1_we = (const float*)d_in[7];
    const float* g1_att= (const float*)d_in[8];
    const float* g1_b  = (const float*)d_in[9];
    const float* n1_g  = (const float*)d_in[10];
    const float* n1_b  = (const float*)d_in[11];
    const float* g2_wl = (const float*)d_in[12];
    const float* g2_wr = (const float*)d_in[13];
    const float* g2_we = (const float*)d_in[14];
    const float* g2_att= (const float*)d_in[15];
    const float* g2_b  = (const float*)d_in[16];
    const float* n2_g  = (const float*)d_in[17];
    const float* n2_b  = (const float*)d_in[18];
    const float* c1_w  = (const float*)d_in[19];
    const float* c1_b  = (const float*)d_in[20];
    const float* c2_w  = (const float*)d_in[21];
    const float* c2_b  = (const float*)d_in[22];
    const float* c3_w  = (const float*)d_in[23];
    const float* c3_b  = (const float*)d_in[24];
    const int* src = edge_index;
    const int* dst = edge_index + NE;

    // ---- workspace layout ----
    char* wsb = (char*)d_ws;
    size_t o = 0;
    auto alloc = [&](size_t bytes) { void* p = wsb + o; o += (bytes + 255) & ~(size_t)255; return p; };
    int* cntS = (int*)alloc(NN * 4);          // cntS+cntD must stay first (one memset)
    int* cntD = (int*)alloc(NN * 4);
    int* curS = (int*)alloc(NN * 4);
    int* curD = (int*)alloc(NN * 4);
    int* rpS  = (int*)alloc((NN + 1) * 4);
    int* rpD  = (int*)alloc((NN + 1) * 4);
    int* eidS = (int*)alloc((size_t)NE * 4);
    int* eidD = (int*)alloc((size_t)NE * 4);
    int* srcS = (int*)alloc((size_t)NE * 4);
    int* dstS = (int*)alloc((size_t)NE * 4);
    float* loopa   = (float*)alloc((size_t)NN * 64 * 4);
    float* x_input = (float*)alloc((size_t)NN * 256 * 4);   // reused: h2
    float* xl1     = (float*)alloc((size_t)NN * 256 * 4);   // reused: xl2, Ps
    float* xr1     = (float*)alloc((size_t)NN * 256 * 4);   // reused: xr2, Pd
    float* logits  = (float*)alloc((size_t)EA * 2 * 4);
    float* h1      = (float*)alloc((size_t)NN * 128 * 4);
    float* xl2 = xl1;
    float* xr2 = xr1;
    float* h2  = x_input;
    float* Ps  = xl1;
    float* Pd  = xr1;

    // ---- CSR build ----
    hipMemsetAsync(d_ws, 0, 2 * ((NN * 4 + 255) & ~255), stream);   // cntS + cntD
    k_hist<<<(NE + 255) / 256, 256, 0, stream>>>(src, dst, cntS, cntD);
    k_scan<<<1, 1024, 0, stream>>>(cntS, cntD, rpS, rpD, curS, curD);
    k_scatter<<<(NE + 255) / 256, 256, 0, stream>>>(src, dst, curS, curD, eidS, eidD, srcS, dstS);

    // ---- stage 1: node input features (1 wave per node) ----
    k_node_inputs<<<NN, 64, 0, stream>>>(edge_attr, rpS, eidS, rpD, eidD,
                                         ep_w, ep_b, x_input, loopa);

    // ---- GAT layer 1 (heads=2) ----
    k_gemm2<256, 256><<<(NN + 63) / 64, 512, 0, stream>>>(x_input, g1_wl, g1_wr, xl1, xr1, NN);
    k_gat_logits<2><<<(EA + 127) / 128, 256, 0, stream>>>(edge_attr, eidD, srcS, dstS, loopa,
                                                          xl1, xr1, g1_we, g1_att, logits);
    k_gat_reduce<2><<<NN, 64, 0, stream>>>(rpD, srcS, xl1, logits, g1_b, n1_g, n1_b, h1);

    // ---- GAT layer 2 (heads=1) ----
    k_gemm2<128, 128><<<(NN + 63) / 64, 512, 0, stream>>>(h1, g2_wl, g2_wr, xl2, xr2, NN);
    k_gat_logits<1><<<(EA + 127) / 128, 256, 0, stream>>>(edge_attr, eidD, srcS, dstS, loopa,
                                                          xl2, xr2, g2_we, g2_att, logits);
    k_gat_reduce<1><<<NN, 64, 0, stream>>>(rpD, srcS, xl2, logits, g2_b, n2_g, n2_b, h2);

    // ---- classifier: node-decomposed layer 1, dst-sorted traversal ----
    k_gemm2<128, 128><<<(NN + 63) / 64, 512, 0, stream>>>(h2, c1_w, c1_w + 128 * 128, Ps, Pd, NN);
    k_classifier<<<(NE + 63) / 64, 256, 0, stream>>>(Ps, Pd, eidD, srcS, dstS, edge_attr,
                                                     c1_w + 256 * 128, c1_b, c2_w, c2_b, c3_w, c3_b,
                                                     (float*)d_out);
}